// Round 2
// 496.260 us; speedup vs baseline: 1.0806x; 1.0806x over previous
//
#include <hip/hip_runtime.h>
#include <cmath>

// B=8, T=4096, D=1024.  M = B*T = 32768.
// Pipeline (uses linearity: prefix(e*(x@Wc_ctx^T)) = prefix(e*x)@Wc_ctx^T):
//   cast_all: x->xb(bf16), W1->W1b, Wc->Wcb (native layout), s:=0
//   s[m]  = w2 . tanh(xb @ W1b^T + b1)        (MFMA, fused epilogue; b2 cancels)
//   e,den = exp(s - max), cumsum per batch    (single-pass block scan)
//   q[t]  = prefix(e*x)[t]/den[t]  (bf16)     (3-pass chunked scan)
//   out   = tanh( [q|x] @ Wcb^T + bc )        (MFMA, K=2048, fused epilogue)
//
// GEMMs: 256x256 tile, BK=64, 8 waves (2Mx4N), double-buffered 128KB LDS,
// counted vmcnt (never 0 in main loop), raw s_barrier phases, setprio around
// MFMA clusters, XOR-swizzled LDS (verified conflict-free), XCD-aware swizzle.
//
// ws layout (float units):
//   s   [0, 32768)           e   [32768, 65536)       den [65536, 98304)
//   S   [98304, 622592)      qb(bf16) [622592, 17399808)
//   xb(bf16) [17399808, 34177024)  W1b [34177024, 34701312)  Wcb [34701312, 35749888)

#define Mtot 32768
#define Dd 1024
#define Tt 4096
#define Bb 8
#define NCHUNK 64
#define TCH 64

typedef __bf16 bf16x8 __attribute__((ext_vector_type(8)));
typedef float f32x4 __attribute__((ext_vector_type(4)));

__device__ __forceinline__ unsigned short f2bf(float f) {
  unsigned int u = __float_as_uint(f);
  unsigned int r = (u + 0x7FFFu + ((u >> 16) & 1u)) >> 16;
  return (unsigned short)r;
}
__device__ __forceinline__ float bf2f(unsigned short s) {
  return __uint_as_float(((unsigned int)s) << 16);
}
// fast tanh: 1 - 2/(e^{2x}+1)   (v_exp_f32 + fast div; rel err ~1e-6)
__device__ __forceinline__ float tanh_fast(float x) {
  return 1.0f - __fdividef(2.0f, __expf(2.0f * x) + 1.0f);
}

__device__ __forceinline__ void gload16(const unsigned short* g, unsigned short* l) {
  __builtin_amdgcn_global_load_lds(
      (const __attribute__((address_space(1))) unsigned int*)g,
      (__attribute__((address_space(3))) unsigned int*)l, 16, 0, 0);
}

// ---- MFMA core: 256x256 tile, BK=64, 8 waves (2x4), dbuf LDS, counted vmcnt ----
// LDS per buffer: A 256x64 bf16 (32KB) + B 256x64 bf16 (32KB); 2 buffers = 128KB.
// Swizzle: LDS[row][cb] holds global col-block cb ^ (row&7)  (8 bf16 blocks/row).
__device__ __forceinline__ void mfma_core256(
    const unsigned short* __restrict__ A0, const unsigned short* __restrict__ A1,
    const unsigned short* __restrict__ W, int ldw, int Ktot,
    int m0, int n0, unsigned short* lds, f32x4 acc[8][4]) {
  const int tid = threadIdx.x;
  const int lane = tid & 63, w = tid >> 6;     // 8 waves
  const int wm = w >> 2, wn = w & 3;           // 2 x 4 wave grid
  const int quad = lane >> 4, c = lane & 15;
  const int lrow = lane >> 3;                  // 0..7
  const int col8 = (lane & 7) ^ lrow;          // pre-swizzled source col-block
  const int NK = Ktot >> 6;

  // stage K-tile kt_ into buffer dst: 4 calls/operand, each wave covers 8 rows/call
#define STG(dst, kt_) do {                                                        \
    int k0_ = (kt_) << 6;                                                         \
    const unsigned short* Asrc_ = (k0_ < 1024) ? A0 : A1;                         \
    int ka_ = k0_ & 1023;                                                         \
    _Pragma("unroll")                                                             \
    for (int j = 0; j < 4; ++j) {                                                 \
      int rb_ = j * 64 + w * 8;                                                   \
      gload16(Asrc_ + (size_t)(m0 + rb_ + lrow) * 1024 + ka_ + col8 * 8,          \
              (dst) + rb_ * 64);                                                  \
      gload16(W + (size_t)(n0 + rb_ + lrow) * ldw + k0_ + col8 * 8,               \
              (dst) + 16384 + rb_ * 64);                                          \
    }                                                                             \
  } while (0)

  STG(lds, 0);  // prologue: 8 loads in flight

#pragma unroll 1
  for (int kt = 0; kt < NK; ++kt) {
    unsigned short* cur = lds + (kt & 1) * 32768;
    unsigned short* nxt = lds + ((kt + 1) & 1) * 32768;
    if (kt + 1 < NK) {
      STG(nxt, kt + 1);  // prefetch next tile (safe: nxt not read this iter)
      asm volatile("s_waitcnt vmcnt(8)" ::: "memory");  // stage(kt) landed, 8 stay in flight
    } else {
      asm volatile("s_waitcnt vmcnt(0)" ::: "memory");  // tail drain
    }
    __builtin_amdgcn_s_barrier();   // all waves see buf[cur] ready
    asm volatile("" ::: "memory");

    const unsigned short* As = cur;
    const unsigned short* Bs = cur + 16384;
    bf16x8 bfr[4];
#pragma unroll
    for (int p = 0; p < 4; ++p) {
      const int ks = p >> 1, mh = p & 1;
      if (mh == 0) {  // B frags for this k-slice (reused by next phase)
#pragma unroll
        for (int jn = 0; jn < 4; ++jn) {
          int rb = wn * 64 + jn * 16 + c;
          int pb = (ks * 4 + quad) ^ (rb & 7);
          bfr[jn] = *(const bf16x8*)(Bs + rb * 64 + pb * 8);
        }
      }
      bf16x8 af[4];
#pragma unroll
      for (int ii = 0; ii < 4; ++ii) {
        int ra = wm * 128 + (mh * 4 + ii) * 16 + c;
        int pa = (ks * 4 + quad) ^ (ra & 7);
        af[ii] = *(const bf16x8*)(As + ra * 64 + pa * 8);
      }
      asm volatile("" ::: "memory");
      __builtin_amdgcn_s_barrier();                       // align waves before MFMA burst
      asm volatile("s_waitcnt lgkmcnt(0)" ::: "memory");  // reads of this phase done
      __builtin_amdgcn_sched_barrier(0);
      __builtin_amdgcn_s_setprio(1);
#pragma unroll
      for (int ii = 0; ii < 4; ++ii)
#pragma unroll
        for (int jn = 0; jn < 4; ++jn)
          acc[mh * 4 + ii][jn] = __builtin_amdgcn_mfma_f32_16x16x32_bf16(
              af[ii], bfr[jn], acc[mh * 4 + ii][jn], 0, 0, 0);
      __builtin_amdgcn_s_setprio(0);
      asm volatile("" ::: "memory");
      __builtin_amdgcn_s_barrier();  // reads of cur complete for ALL waves past here
      asm volatile("" ::: "memory");
    }
  }
#undef STG
}

// ---- GEMM 1: s[m] = sum_n w2[n]*tanh((x@W1^T)[m][n] + b1[n]) ----
__global__ __launch_bounds__(512, 2) void gemm_s(
    const unsigned short* __restrict__ xb, const unsigned short* __restrict__ W1b,
    const float* __restrict__ b1, const float* __restrict__ w2, float* __restrict__ s) {
  __shared__ __align__(16) unsigned short lds[65536];  // 128KB
  f32x4 acc[8][4];
#pragma unroll
  for (int i = 0; i < 8; ++i)
#pragma unroll
    for (int j = 0; j < 4; ++j) acc[i][j] = (f32x4){0.f, 0.f, 0.f, 0.f};
  // XCD-aware bijective swizzle (nwg=512, 512%8==0)
  int bid = blockIdx.x;
  int swz = (bid & 7) * 64 + (bid >> 3);
  int m0 = (swz >> 2) * 256, n0 = (swz & 3) * 256;
  mfma_core256(xb, xb, W1b, 1024, 1024, m0, n0, lds, acc);
  int tid = threadIdx.x, lane = tid & 63, w = tid >> 6;
  int wm = w >> 2, wn = w & 3, quad = lane >> 4, c = lane & 15;
  float w2v[4], b1v[4];
#pragma unroll
  for (int jn = 0; jn < 4; ++jn) {
    int n = n0 + wn * 64 + jn * 16 + c;
    w2v[jn] = w2[n];
    b1v[jn] = b1[n];
  }
#pragma unroll
  for (int i = 0; i < 8; ++i) {
#pragma unroll
    for (int r = 0; r < 4; ++r) {
      float p = 0.f;
#pragma unroll
      for (int jn = 0; jn < 4; ++jn) p += w2v[jn] * tanh_fast(acc[i][jn][r] + b1v[jn]);
      p += __shfl_xor(p, 1, 64);
      p += __shfl_xor(p, 2, 64);
      p += __shfl_xor(p, 4, 64);
      p += __shfl_xor(p, 8, 64);
      if (c == 0) atomicAdd(&s[m0 + wm * 128 + i * 16 + quad * 4 + r], p);
    }
  }
}

// ---- GEMM 2: out = tanh([q|x] @ Wc^T + bc), K=2048 ----
__global__ __launch_bounds__(512, 2) void gemm_out(
    const unsigned short* __restrict__ qb, const unsigned short* __restrict__ xb,
    const unsigned short* __restrict__ Wcb, const float* __restrict__ bc_,
    float* __restrict__ out) {
  __shared__ __align__(16) unsigned short lds[65536];  // 128KB
  f32x4 acc[8][4];
#pragma unroll
  for (int i = 0; i < 8; ++i)
#pragma unroll
    for (int j = 0; j < 4; ++j) acc[i][j] = (f32x4){0.f, 0.f, 0.f, 0.f};
  int bid = blockIdx.x;
  int swz = (bid & 7) * 64 + (bid >> 3);
  int m0 = (swz >> 2) * 256, n0 = (swz & 3) * 256;
  mfma_core256(qb, xb, Wcb, 2048, 2048, m0, n0, lds, acc);
  int tid = threadIdx.x, lane = tid & 63, w = tid >> 6;
  int wm = w >> 2, wn = w & 3, quad = lane >> 4, c = lane & 15;
#pragma unroll
  for (int jn = 0; jn < 4; ++jn) {
    int n = n0 + wn * 64 + jn * 16 + c;
    float bias = bc_[n];
#pragma unroll
    for (int i = 0; i < 8; ++i) {
#pragma unroll
      for (int r = 0; r < 4; ++r) {
        int m = m0 + wm * 128 + i * 16 + quad * 4 + r;
        out[(size_t)m * Dd + n] = tanh_fast(acc[i][jn][r] + bias);
      }
    }
  }
}

// ---- merged cast + zero: x->xb, W1->W1b, Wc->Wcb, s:=0 ----
__global__ __launch_bounds__(256) void cast_all(
    const float4* __restrict__ x, const float4* __restrict__ W1,
    const float4* __restrict__ Wc, ushort4* __restrict__ xb,
    ushort4* __restrict__ W1b, ushort4* __restrict__ Wcb,
    float4* __restrict__ s) {
  int i = blockIdx.x * 256 + threadIdx.x;
  if (i < 8388608) {
    float4 v = x[i];
    ushort4 o;
    o.x = f2bf(v.x); o.y = f2bf(v.y); o.z = f2bf(v.z); o.w = f2bf(v.w);
    xb[i] = o;
  } else if (i < 8650752) {
    int p = i - 8388608;
    float4 v = W1[p];
    ushort4 o;
    o.x = f2bf(v.x); o.y = f2bf(v.y); o.z = f2bf(v.z); o.w = f2bf(v.w);
    W1b[p] = o;
  } else if (i < 9175040) {
    int p = i - 8650752;
    float4 v = Wc[p];
    ushort4 o;
    o.x = f2bf(v.x); o.y = f2bf(v.y); o.z = f2bf(v.z); o.w = f2bf(v.w);
    Wcb[p] = o;
  } else {
    s[i - 9175040] = (float4){0.f, 0.f, 0.f, 0.f};
  }
}

// ---- softmax + cumsum(e): one block/batch, 16 elems/thread, single pass ----
__global__ __launch_bounds__(256) void softmax_scan(
    const float* __restrict__ s, float* __restrict__ e, float* __restrict__ den) {
  int b = blockIdx.x, tid = threadIdx.x;
  int lane = tid & 63, wid = tid >> 6;
  __shared__ float redm[4], wsum[4];
  const float4* sb4 = (const float4*)(s + (size_t)b * Tt);
  float v[16];
#pragma unroll
  for (int j = 0; j < 4; ++j) {
    float4 f = sb4[tid * 4 + j];
    v[j * 4 + 0] = f.x; v[j * 4 + 1] = f.y; v[j * 4 + 2] = f.z; v[j * 4 + 3] = f.w;
  }
  float m = v[0];
#pragma unroll
  for (int j = 1; j < 16; ++j) m = fmaxf(m, v[j]);
#pragma unroll
  for (int off = 32; off > 0; off >>= 1) m = fmaxf(m, __shfl_xor(m, off, 64));
  if (lane == 0) redm[wid] = m;
  __syncthreads();
  m = fmaxf(fmaxf(redm[0], redm[1]), fmaxf(redm[2], redm[3]));
  float ev[16];
  float ls = 0.f;
#pragma unroll
  for (int j = 0; j < 16; ++j) { ev[j] = __expf(v[j] - m); ls += ev[j]; }
  // inclusive wave scan of ls
  float sc = ls;
#pragma unroll
  for (int off = 1; off < 64; off <<= 1) {
    float tt = __shfl_up(sc, off, 64);
    if (lane >= off) sc += tt;
  }
  if (lane == 63) wsum[wid] = sc;
  __syncthreads();
  float woff = 0.f;
#pragma unroll
  for (int w = 0; w < 4; ++w) woff += (w < wid) ? wsum[w] : 0.f;
  float run = sc - ls + woff;  // exclusive prefix for this thread
  float4* eb4 = (float4*)(e + (size_t)b * Tt);
  float4* db4 = (float4*)(den + (size_t)b * Tt);
#pragma unroll
  for (int j = 0; j < 4; ++j) {
    float4 eo, doo;
    run += ev[j * 4 + 0]; eo.x = ev[j * 4 + 0]; doo.x = run;
    run += ev[j * 4 + 1]; eo.y = ev[j * 4 + 1]; doo.y = run;
    run += ev[j * 4 + 2]; eo.z = ev[j * 4 + 2]; doo.z = run;
    run += ev[j * 4 + 3]; eo.w = ev[j * 4 + 3]; doo.w = run;
    eb4[tid * 4 + j] = eo;
    db4[tid * 4 + j] = doo;
  }
}

// ---- scan pass A: chunk partial sums of e*x ----
__global__ __launch_bounds__(1024) void chunk_sums(
    const unsigned short* __restrict__ xb, const float* __restrict__ e,
    float* __restrict__ S) {
  int bc = blockIdx.x;
  int b = bc >> 6, c = bc & 63;
  int d = threadIdx.x;
  const unsigned short* xp = xb + ((size_t)(b * Tt + c * TCH)) * Dd + d;
  const float* eb = e + (size_t)b * Tt + c * TCH;
  float acc = 0.f;
#pragma unroll 8
  for (int t = 0; t < TCH; ++t) acc += eb[t] * bf2f(xp[(size_t)t * Dd]);
  S[((size_t)bc) * Dd + d] = acc;
}

// ---- scan pass B: exclusive prefix over chunks ----
__global__ __launch_bounds__(256) void chunk_prefix(float* __restrict__ S) {
  int idx = blockIdx.x * 256 + threadIdx.x;  // over Bb*Dd = 8192
  int b = idx >> 10, d = idx & 1023;
  float* Sb = S + (size_t)b * NCHUNK * Dd + d;
  float acc = 0.f;
#pragma unroll 8
  for (int c = 0; c < NCHUNK; ++c) {
    float t = Sb[(size_t)c * Dd];
    Sb[(size_t)c * Dd] = acc;
    acc += t;
  }
}

// ---- scan pass C: finish prefix, q = prefix(e*x)/den -> bf16 ----
__global__ __launch_bounds__(1024) void scan_q(
    const unsigned short* __restrict__ xb, const float* __restrict__ e,
    const float* __restrict__ den, const float* __restrict__ S,
    unsigned short* __restrict__ qb) {
  int bc = blockIdx.x;
  int b = bc >> 6, c = bc & 63;
  int d = threadIdx.x;
  int tbase = b * Tt + c * TCH;
  float acc = S[((size_t)bc) * Dd + d];
  const unsigned short* xp = xb + (size_t)tbase * Dd + d;
  const float* eb = e + tbase;
  const float* db = den + tbase;
  unsigned short* qp = qb + (size_t)tbase * Dd + d;
#pragma unroll 4
  for (int t = 0; t < TCH; ++t) {
    acc += eb[t] * bf2f(xp[(size_t)t * Dd]);
    qp[(size_t)t * Dd] = f2bf(acc * __fdividef(1.0f, db[t]));
  }
}

extern "C" void kernel_launch(void* const* d_in, const int* in_sizes, int n_in,
                              void* d_out, int out_size, void* d_ws, size_t ws_size,
                              hipStream_t stream) {
  const float* x  = (const float*)d_in[0];
  const float* W1 = (const float*)d_in[1];
  const float* b1 = (const float*)d_in[2];
  const float* w2 = (const float*)d_in[3];
  // d_in[4] = b2 : cancels under softmax shift invariance
  const float* Wc = (const float*)d_in[5];
  const float* bc = (const float*)d_in[6];
  float* out = (float*)d_out;

  float* ws = (float*)d_ws;
  float* s_buf   = ws;                       // 32768
  float* e_buf   = ws + 32768;               // 32768
  float* den_buf = ws + 65536;               // 32768
  float* S_buf   = ws + 98304;               // 524288
  unsigned short* qb  = (unsigned short*)(ws + 622592);    // 33554432 bf16
  unsigned short* xb  = (unsigned short*)(ws + 17399808);  // 33554432 bf16
  unsigned short* W1b = (unsigned short*)(ws + 34177024);  // 1048576 bf16
  unsigned short* Wcb = (unsigned short*)(ws + 34701312);  // 2097152 bf16

  cast_all<<<35872, 256, 0, stream>>>((const float4*)x, (const float4*)W1,
                                      (const float4*)Wc, (ushort4*)xb,
                                      (ushort4*)W1b, (ushort4*)Wcb,
                                      (float4*)s_buf);

  gemm_s<<<512, 512, 0, stream>>>(xb, W1b, b1, w2, s_buf);
  softmax_scan<<<Bb, 256, 0, stream>>>(s_buf, e_buf, den_buf);
  chunk_sums<<<Bb * NCHUNK, 1024, 0, stream>>>(xb, e_buf, S_buf);
  chunk_prefix<<<Bb * Dd / 256, 256, 0, stream>>>(S_buf);
  scan_q<<<Bb * NCHUNK, 1024, 0, stream>>>(xb, e_buf, den_buf, S_buf, qb);
  gemm_out<<<512, 512, 0, stream>>>(qb, xb, Wcb, bc, out);
}